// Round 8
// baseline (212.944 us; speedup 1.0000x reference)
//
#include <hip/hip_runtime.h>
#include <hip/hip_bf16.h>

#define B_    256
#define NKV   128
#define NQ    512
#define CDIM  192
#define QCDIM 96
#define NH    6
#define DH    32
#define SCALE 0.17677669529663687f
#define LOG2E 1.4426950408889634f

typedef __hip_bfloat16 bf16;
typedef __attribute__((ext_vector_type(8))) short s16x8;
typedef __attribute__((ext_vector_type(4))) short s16x4;
typedef __attribute__((ext_vector_type(4))) float f32x4;
#define MFMA16(a, b, c) __builtin_amdgcn_mfma_f32_16x16x32_bf16(a, b, c, 0, 0, 0)

__device__ __forceinline__ float b2f(short s) {
    return __uint_as_float(((unsigned)(unsigned short)s) << 16);
}

// ---- workspace layout (bytes). *F tensors are MFMA-fragment-ordered:
// [...frag...][lane(64)][elems] so a wave reads one fragment as one coalesced
// global_load. biasF is bf16. wqF/biasF pre-scaled by LOG2E. ----
#define OFF_BIASF 0                        // bf16 [6][32][8][64][4]     = 786,432
#define OFF_WKVF  786432                   // bf16 [24][6][64][8]        = 147,456
#define OFF_WQF   933888                   // bf16 [6][2][3][64][8]      = 36,864 (×SCALE×LOG2E)
#define OFF_WPF   970752                   // bf16 [6][6][64][8]         = 36,864
#define OFF_KF    1007616                  // bf16 [B_][6][8][64][8]     = 12,582,912
#define OFF_VF    13590528                 // bf16 [B_][6][2][4][64][8]  = 12,582,912
// total 26,173,440 B

// One kernel for all precomputation: biasF (98304 thr) + wkvF/wqF/wpF (110592 thr)
__global__ __launch_bounds__(256)
void precomp_all(const float* __restrict__ w_kv, const float* __restrict__ w_q,
                 const float* __restrict__ w_proj, const float* __restrict__ bias_table,
                 const int* __restrict__ rel_index,
                 bf16* __restrict__ biasF, bf16* __restrict__ wkvF,
                 bf16* __restrict__ wqF, bf16* __restrict__ wpF)
{
    const int i = blockIdx.x * 256 + threadIdx.x;   // 208896 total
    if (i < 98304) {                                // biasF[h][rowblk][tl][lane][r]  (bf16)
        const int lane = i & 63, tl = (i >> 6) & 7, rowblk = (i >> 9) & 31, h = i >> 14;
        const int quad = lane >> 4, l16 = lane & 15;
        const int kvi = tl * 16 + l16;
        __align__(8) bf16 vr[4];
        #pragma unroll
        for (int r = 0; r < 4; ++r) {
            const int qrow = rowblk * 16 + quad * 4 + r;
            vr[r] = __float2bfloat16(bias_table[rel_index[qrow * NKV + kvi] * NH + h] * LOG2E);
        }
        *(uint2*)&biasF[i * 4] = *(uint2*)vr;
    } else if (i < 98304 + 73728) {                 // wkvF[nt24][kk6][lane][j]
        const int i1 = i - 98304;
        const int j = i1 & 7, lane = (i1 >> 3) & 63, kk = (i1 >> 9) % 6, nt = i1 / 3072;
        const int quad = lane >> 4, l16 = lane & 15;
        wkvF[i1] = __float2bfloat16(w_kv[(kk * 32 + quad * 8 + j) * (2 * CDIM) + nt * 16 + l16]);
    } else if (i < 98304 + 92160) {                 // wqF[h][tl2][kk3][lane][j]
        const int i2 = i - 98304 - 73728;
        const int j = i2 & 7, lane = (i2 >> 3) & 63, kk = (i2 >> 9) % 3,
                  tl = (i2 / 1536) & 1, h = i2 / 3072;
        const int quad = lane >> 4, l16 = lane & 15;
        wqF[i2] = __float2bfloat16(w_q[(kk * 32 + quad * 8 + j) * CDIM + h * DH + tl * 16 + l16]
                                   * (SCALE * LOG2E));
    } else {                                        // wpF[h][tn6][lane][j]
        const int i3 = i - 98304 - 92160;
        const int j = i3 & 7, lane = (i3 >> 3) & 63, tn = (i3 >> 9) % 6, h = i3 / 3072;
        const int quad = lane >> 4, l16 = lane & 15;
        wpF[i3] = __float2bfloat16(w_proj[(h * DH + quad * 8 + j) * QCDIM + tn * 16 + l16]);
    }
}

// Per (batch, half, rowhalf): grid (256,2,2) = 1024 blocks, 256 thr (4 waves),
// each block projects 64 kv rows for one output half (K or V).
// R6-lesson restructure of the old 512x512 version (which had 2 blocks/CU and
// 72 un-prefetched fragment loads inside the MFMA loop — the same latency
// disease attn_fused had): wkvF fragments are register-prefetched one k-step
// ahead (fA/fB ping-pong, statically indexed), LDS halved to 27.6 KB.
// Output tiles decompose per row-half: KF tl in {4*half2..+3}; VF kk in
// {2*half2, 2*half2+1}.
__global__ __launch_bounds__(256, 3)
void proj_kv(const float* __restrict__ kv, const float* __restrict__ b_kv,
             const bf16* __restrict__ wkvF, bf16* __restrict__ KF, bf16* __restrict__ VF)
{
    __shared__ __align__(16) char smem[27648];
    bf16* sA = (bf16*)smem;                        // staging [64][200]
    const int b = blockIdx.x, half = blockIdx.y, half2 = blockIdx.z, t = threadIdx.x;
    const int w = t >> 6, lane = t & 63, quad = lane >> 4, l16 = lane & 15;
    const f32x4 ZV = {0.f, 0.f, 0.f, 0.f};

    // stage this block's 64 kv rows, fp32 -> bf16
    for (int f = t; f < 3072; f += 256) {
        const int r = f / 48, c4 = f % 48;
        const float4 v = *(const float4*)&kv[((size_t)b * NKV + half2 * 64 + r) * CDIM + c4 * 4];
        __align__(8) bf16 tmp[4] = {__float2bfloat16(v.x), __float2bfloat16(v.y),
                                    __float2bfloat16(v.z), __float2bfloat16(v.w)};
        *(uint2*)&sA[r * 200 + c4 * 4] = *(uint2*)tmp;
    }

    // hoist the 12 output-column biases for this half
    float bias[12];
    #pragma unroll
    for (int nt = 0; nt < 12; ++nt) bias[nt] = b_kv[half * CDIM + nt * 16 + l16];

    __syncthreads();

    f32x4 acc[12];
    #pragma unroll
    for (int i = 0; i < 12; ++i) acc[i] = ZV;

    // register-prefetched fragment stream: fA holds k-step kk, fB holds kk+1
    s16x8 fA[12], fB[12];
    #pragma unroll
    for (int nt = 0; nt < 12; ++nt)
        fA[nt] = *(const s16x8*)&wkvF[(((half * 12 + nt) * 6 + 0) * 64 + lane) * 8];
    #pragma unroll
    for (int kk = 0; kk < 6; kk += 2) {
        #pragma unroll
        for (int nt = 0; nt < 12; ++nt)
            fB[nt] = *(const s16x8*)&wkvF[(((half * 12 + nt) * 6 + kk + 1) * 64 + lane) * 8];
        const s16x8 a0 = *(const s16x8*)&sA[(w * 16 + l16) * 200 + kk * 32 + quad * 8];
        #pragma unroll
        for (int nt = 0; nt < 12; ++nt) acc[nt] = MFMA16(a0, fA[nt], acc[nt]);
        if (kk + 2 < 6) {
            #pragma unroll
            for (int nt = 0; nt < 12; ++nt)
                fA[nt] = *(const s16x8*)&wkvF[(((half * 12 + nt) * 6 + kk + 2) * 64 + lane) * 8];
        }
        const s16x8 a1 = *(const s16x8*)&sA[(w * 16 + l16) * 200 + (kk + 1) * 32 + quad * 8];
        #pragma unroll
        for (int nt = 0; nt < 12; ++nt) acc[nt] = MFMA16(a1, fB[nt], acc[nt]);
    }
    __syncthreads();   // staging dead; reuse smem as transpose buffer

    if (half == 0) {
        bf16* bufK = (bf16*)smem;                  // K' local [64][200]
        #pragma unroll
        for (int nt = 0; nt < 12; ++nt) {
            const int col = nt * 16 + l16;
            #pragma unroll
            for (int r = 0; r < 4; ++r)
                bufK[(w * 16 + quad * 4 + r) * 200 + col] = __float2bfloat16(acc[nt][r] + bias[nt]);
        }
        __syncthreads();
        bf16* KF_b = KF + (size_t)b * 24576;       // [h][tl8][lane][8]
        #pragma unroll
        for (int i = 0; i < 6; ++i) {
            const int fl = w * 6 + i;              // 0..23
            const int h = fl >> 2, tll = fl & 3, tl = half2 * 4 + tll;
            const s16x8 v = *(const s16x8*)&bufK[(tll * 16 + l16) * 200 + h * DH + quad * 8];
            *(s16x8*)&KF_b[(size_t)((h * 8 + tl) * 64 + lane) * 8] = v;
        }
    } else {
        bf16* bufV = (bf16*)smem;                  // V'^T local [192][72]
        #pragma unroll
        for (int nt = 0; nt < 12; ++nt) {
            const int d = nt * 16 + l16;
            __align__(8) bf16 tmp[4];
            #pragma unroll
            for (int r = 0; r < 4; ++r) tmp[r] = __float2bfloat16(acc[nt][r] + bias[nt]);
            *(uint2*)&bufV[d * 72 + w * 16 + quad * 4] = *(uint2*)tmp;
        }
        __syncthreads();
        bf16* VF_b = VF + (size_t)b * 24576;       // [h][tl2][kk4][lane][8]
        #pragma unroll
        for (int i = 0; i < 6; ++i) {
            const int fl = w * 6 + i;              // 0..23
            const int h = fl >> 2, rest = fl & 3, tl = rest >> 1, kkl = rest & 1;
            const int kk = half2 * 2 + kkl;
            const s16x8 v = *(const s16x8*)&bufV[(h * DH + tl * 16 + l16) * 72 + kkl * 32 + quad * 8];
            *(s16x8*)&VF_b[(size_t)(((h * 2 + tl) * 4 + kk) * 64 + lane) * 8] = v;
        }
    }
}

// Per (batch, 16-row chain): grid (B, 8), 4 waves, each wave ONE chain.
// PREFETCH-STRUCTURED: all of head h's B-side fragments are issued in source
// order ahead of their consuming phase (KF/bias/wq up front; VF during the Q'
// LDS bounce; wp during the P bounce) so L2 latency hides under compute.
// launch_bounds(256,4): 128-reg budget for the prefetch window; LDS 17.4 KB.
// (UNCHANGED from the 90.5 µs round-6 version.)
__global__ __launch_bounds__(256, 4)
void attn_fused(const float* __restrict__ q, const float* __restrict__ b_q,
                const float* __restrict__ b_proj, const char* __restrict__ wsro,
                float* __restrict__ out)
{
    __shared__ __align__(16) bf16 sP[4 * 16 * 136];   // 17,408 B
    const int b = blockIdx.x, y = blockIdx.y;         // y in 0..7
    const int t = threadIdx.x;
    const int w = t >> 6, lane = t & 63, quad = lane >> 4, l16 = lane & 15;

    const bf16* biasF = (const bf16*)(wsro + OFF_BIASF);
    const bf16* wqF   = (const bf16*)(wsro + OFF_WQF);
    const bf16* wpF   = (const bf16*)(wsro + OFF_WPF);
    const bf16* KF_b  = (const bf16*)(wsro + OFF_KF) + (size_t)b * 24576;
    const bf16* VF_b  = (const bf16*)(wsro + OFF_VF) + (size_t)b * 24576;

    const int rb = y * 4 + w;                         // row-block 0..31
    bf16* myP = sP + w * 2176;

    // q A-fragments, fp32 -> bf16 in-kernel
    s16x8 qa[3];
    #pragma unroll
    for (int kk = 0; kk < 3; ++kk) {
        const float* src = &q[((size_t)b * NQ + rb * 16 + l16) * QCDIM + kk * 32 + quad * 8];
        const float4 a0 = *(const float4*)src;
        const float4 a1 = *(const float4*)(src + 4);
        __align__(16) bf16 tmp[8] = {
            __float2bfloat16(a0.x), __float2bfloat16(a0.y), __float2bfloat16(a0.z),
            __float2bfloat16(a0.w), __float2bfloat16(a1.x), __float2bfloat16(a1.y),
            __float2bfloat16(a1.z), __float2bfloat16(a1.w)};
        qa[kk] = *(s16x8*)tmp;
    }

    // out accumulator initialized with b_proj (folds the epilogue bias add)
    f32x4 outacc[6];
    #pragma unroll
    for (int tn = 0; tn < 6; ++tn) {
        const float bp = b_proj[tn * 16 + l16];
        outacc[tn] = (f32x4){bp, bp, bp, bp};
    }

    for (int h = 0; h < NH; ++h) {
        // ---- issue S-phase loads FIRST: KF(8) + bias(8, bf16) + wq(6) ----
        s16x8 kf[8];
        #pragma unroll
        for (int t4 = 0; t4 < 8; ++t4)
            kf[t4] = *(const s16x8*)&KF_b[(size_t)((h * 8 + t4) * 64 + lane) * 8];
        s16x4 bb[8];
        #pragma unroll
        for (int t4 = 0; t4 < 8; ++t4)
            bb[t4] = *(const s16x4*)&biasF[(((h * 32 + rb) * 8 + t4) * 64 + lane) * 4];
        s16x8 wqf[6];
        #pragma unroll
        for (int i = 0; i < 6; ++i)
            wqf[i] = *(const s16x8*)&wqF[((h * 6 + i) * 64 + lane) * 8];

        // ---- (a) Q'_h = q @ wq_h (pre-scaled SCALE*LOG2E) + b_q splat ----
        f32x4 qacc[2];
        #pragma unroll
        for (int tl = 0; tl < 2; ++tl) {
            const float bq = b_q[h * DH + tl * 16 + l16] * (SCALE * LOG2E);
            qacc[tl] = (f32x4){bq, bq, bq, bq};
        }
        #pragma unroll
        for (int kk = 0; kk < 3; ++kk)
            #pragma unroll
            for (int tl = 0; tl < 2; ++tl)
                qacc[tl] = MFMA16(qa[kk], wqf[tl * 3 + kk], qacc[tl]);
        #pragma unroll
        for (int tl = 0; tl < 2; ++tl)
            #pragma unroll
            for (int r = 0; r < 4; ++r)
                myP[(quad * 4 + r) * 136 + tl * 16 + l16] = __float2bfloat16(qacc[tl][r]);

        // ---- issue V fragments now (consumed after the exp phase) ----
        s16x8 vf[8];
        #pragma unroll
        for (int i = 0; i < 8; ++i)
            vf[i] = *(const s16x8*)&VF_b[(size_t)((h * 8 + i) * 64 + lane) * 8];

        const s16x8 aQ = *(const s16x8*)&myP[l16 * 136 + quad * 8];

        // ---- (b) S = Q'K'^T + bias (bf16 C-init); 2^S; P; row-sums ----
        f32x4 sacc[8];
        #pragma unroll
        for (int t4 = 0; t4 < 8; ++t4)
            #pragma unroll
            for (int r = 0; r < 4; ++r)
                sacc[t4][r] = b2f(bb[t4][r]);
        #pragma unroll
        for (int t4 = 0; t4 < 8; ++t4)
            sacc[t4] = MFMA16(aQ, kf[t4], sacc[t4]);
        float rs[4] = {0.f, 0.f, 0.f, 0.f};
        #pragma unroll
        for (int t4 = 0; t4 < 8; ++t4)
            #pragma unroll
            for (int r = 0; r < 4; ++r) {
                const float vv = __builtin_amdgcn_exp2f(sacc[t4][r]);
                rs[r] += vv;
                myP[(quad * 4 + r) * 136 + t4 * 16 + l16] = __float2bfloat16(vv);
            }

        // ---- issue out-proj fragments (consumed after PV) ----
        s16x8 wpf[6];
        #pragma unroll
        for (int i = 0; i < 6; ++i)
            wpf[i] = *(const s16x8*)&wpF[((h * 6 + i) * 64 + lane) * 8];

        float inv[4];
        #pragma unroll
        for (int r = 0; r < 4; ++r) {
            float s = rs[r];
            #pragma unroll
            for (int off = 1; off < 16; off <<= 1) s += __shfl_xor(s, off, 16);
            inv[r] = 1.f / s;
        }

        // ---- (c) O_h = P_unnorm @ V'_h, scaled by inv ----
        f32x4 oacc[2];
        oacc[0] = (f32x4){0.f, 0.f, 0.f, 0.f};
        oacc[1] = (f32x4){0.f, 0.f, 0.f, 0.f};
        #pragma unroll
        for (int kk = 0; kk < 4; ++kk) {
            const s16x8 aP = *(const s16x8*)&myP[l16 * 136 + kk * 32 + quad * 8];
            #pragma unroll
            for (int tl = 0; tl < 2; ++tl)
                oacc[tl] = MFMA16(aP, vf[tl * 4 + kk], oacc[tl]);
        }
        #pragma unroll
        for (int tl = 0; tl < 2; ++tl)
            #pragma unroll
            for (int r = 0; r < 4; ++r)
                myP[(quad * 4 + r) * 136 + tl * 16 + l16] = __float2bfloat16(oacc[tl][r] * inv[r]);

        // ---- (d) out += O_h @ wp_h ----
        const s16x8 aO = *(const s16x8*)&myP[l16 * 136 + quad * 8];
        #pragma unroll
        for (int tn = 0; tn < 6; ++tn)
            outacc[tn] = MFMA16(aO, wpf[tn], outacc[tn]);
    }

    #pragma unroll
    for (int tn = 0; tn < 6; ++tn)
        #pragma unroll
        for (int r = 0; r < 4; ++r)
            out[((size_t)b * NQ + rb * 16 + quad * 4 + r) * QCDIM + tn * 16 + l16]
                = outacc[tn][r];
}

extern "C" void kernel_launch(void* const* d_in, const int* in_sizes, int n_in,
                              void* d_out, int out_size, void* d_ws, size_t ws_size,
                              hipStream_t stream)
{
    const float* kv       = (const float*)d_in[0];
    const float* q        = (const float*)d_in[1];
    const float* w_kv     = (const float*)d_in[2];
    const float* b_kv     = (const float*)d_in[3];
    const float* w_q      = (const float*)d_in[4];
    const float* b_q      = (const float*)d_in[5];
    const float* w_proj   = (const float*)d_in[6];
    const float* b_proj   = (const float*)d_in[7];
    const float* bias_tab = (const float*)d_in[8];
    const int*   rel_idx  = (const int*)d_in[9];
    char* ws = (char*)d_ws;

    precomp_all<<<816, 256, 0, stream>>>(w_kv, w_q, w_proj, bias_tab, rel_idx,
                                         (bf16*)(ws + OFF_BIASF), (bf16*)(ws + OFF_WKVF),
                                         (bf16*)(ws + OFF_WQF), (bf16*)(ws + OFF_WPF));
    proj_kv<<<dim3(B_, 2, 2), 256, 0, stream>>>(kv, b_kv, (const bf16*)(ws + OFF_WKVF),
                                                (bf16*)(ws + OFF_KF), (bf16*)(ws + OFF_VF));
    attn_fused<<<dim3(B_, 8), 256, 0, stream>>>(q, b_q, b_proj, (const char*)ws,
                                                (float*)d_out);
}